// Round 21
// baseline (512.983 us; speedup 1.0000x reference)
//
#include <hip/hip_runtime.h>

// SingleScaleSA: B=4, N=16384, S=2048, K=32, mlp 64 -> 64 -> 128, radius 0.2.
// FP32 I/O. Round 21: 64-row blocks, single K pass (no chunk loop -> no VGPR
// blowup), LDS ~34K (L1/L2, 4 blocks/CU) / ~52K (L3, 3 blocks/CU).
// Layer3 group max-pool is two-stage (wave shuffle -> sPool LDS combine).
constexpr int kNB    = 4;
constexpr int kNPts  = 16384;
constexpr int kNS    = 2048;
constexpr int kNK    = 32;
constexpr int kC3    = 128;
constexpr int kNRows = kNB * kNS * kNK;   // 262144
constexpr int kNGrp  = kNB * kNS;         // 8192
constexpr double kR2 = 0.2 * 0.2;

// ---------------------------------------------------------------- prep
__global__ __launch_bounds__(256) void ssaPrepKernel(
    const float* xyz, const float* newXyz,
    float* outHead, float4* soa, float* stats)
{
    int t = static_cast<int>(blockIdx.x) * 256 + static_cast<int>(threadIdx.x);
    if (t < kNB * kNPts) {
        soa[t] = make_float4(xyz[t * 3 + 0], xyz[t * 3 + 1], xyz[t * 3 + 2], 0.0f);
    }
    if (t < kNB * kNS * 3) {
        outHead[t] = newXyz[t];
    }
    if (t < 512) {
        stats[t] = 0.0f;
    }
}

// ---------------------------------------------------------------- ball query
__global__ __launch_bounds__(256) void ssaBallKernel(
    const float* newXyz, const float4* soa,
    int* ballIdx, float4* ballDxyz)
{
    int tid  = static_cast<int>(threadIdx.x);
    int w    = (static_cast<int>(blockIdx.x) * 256 + tid) >> 6;
    int lane = tid & 63;
    int b    = w >> 11;
    float qx = newXyz[w * 3 + 0];
    float qy = newXyz[w * 3 + 1];
    float qz = newXyz[w * 3 + 2];
    double qxd = static_cast<double>(qx);
    double qyd = static_cast<double>(qy);
    double qzd = static_cast<double>(qz);
    double qq  = qxd * qxd + qyd * qyd + qzd * qzd;
    const float4* sp = soa + b * kNPts;
    int*    oi = ballIdx  + static_cast<size_t>(w) * kNK;
    float4* od = ballDxyz + static_cast<size_t>(w) * kNK;

    int cnt = 0;
    int firstN = -1;
    float fdx = 0.0f, fdy = 0.0f, fdz = 0.0f;
    for (int base = 0; base < kNPts && cnt < kNK; base += 64) {
        float4 p = sp[base + lane];
        double pxd = static_cast<double>(p.x);
        double pyd = static_cast<double>(p.y);
        double pzd = static_cast<double>(p.z);
        double d2  = qq + (pxd * pxd + pyd * pyd + pzd * pzd)
                   - 2.0 * (qxd * pxd + qyd * pyd + qzd * pzd);
        bool hit   = (d2 <= kR2);
        unsigned long long m = __ballot(hit);
        int pos = cnt + __popcll(m & ((1ull << lane) - 1ull));
        if (hit && pos < kNK) {
            float dx = p.x - qx;
            float dy = p.y - qy;
            float dz = p.z - qz;
            oi[pos] = base + lane;
            od[pos] = make_float4(dx, dy, dz, 0.0f);
            if (pos == 0) { firstN = base + lane; fdx = dx; fdy = dy; fdz = dz; }
        }
        cnt += __popcll(m);
    }
    if (cnt < kNK) {
        unsigned long long hv = __ballot(firstN >= 0);
        int fi;
        float dx, dy, dz;
        if (hv != 0ull) {
            int src = __builtin_ctzll(hv);
            fi = __shfl(firstN, src);
            dx = __shfl(fdx, src);
            dy = __shfl(fdy, src);
            dz = __shfl(fdz, src);
        } else {
            float4 p = sp[kNPts - 1];
            fi = kNPts - 1;
            dx = p.x - qx;
            dy = p.y - qy;
            dz = p.z - qz;
        }
        for (int p2 = cnt + lane; p2 < kNK; p2 += 64) {
            oi[p2] = fi;
            od[p2] = make_float4(dx, dy, dz, 0.0f);
        }
    }
}

// ---------------------------------------------------------------- layer 1
// 64 rows x 64 cols per block; X = [dxyz | gathered points] (K=67) staged
// transposed; fused per-channel stats -> stats[0..63] sum, [64..127] sq.
__global__ __launch_bounds__(256) void ssaLayer1Kernel(
    const float4* points, const float* w1, const float* bias1,
    const int* ballIdx, const float4* ballDxyz, float4* z1, float* stats)
{
    __shared__ float xT[67 * 64];     // ~17 KB
    __shared__ float sW[67 * 64];     // ~17 KB
    __shared__ float sB[64];
    __shared__ float sStat[128];
    int tid = static_cast<int>(threadIdx.x);
    int R0  = static_cast<int>(blockIdx.x) * 64;

    for (int i = tid; i < 67 * 64; i += 256) {
        int k = i >> 6;
        int c = i & 63;
        sW[i] = w1[c * 67 + k];
    }
    if (tid < 64)  sB[tid] = bias1[tid];
    if (tid < 128) sStat[tid] = 0.0f;

    {   // gather + transposed X
        int r = tid & 63;
        int h = tid >> 6;           // 0..3, each loads 4 float4 of the row
        int gi = ballIdx[R0 + r];
        int b  = (R0 + r) >> 16;
        const float4* prow = points + (static_cast<size_t>(b) * kNPts + static_cast<size_t>(gi)) * 16;
        if (h == 0) {
            float4 d = ballDxyz[R0 + r];
            xT[0 * 64 + r] = d.x;
            xT[1 * 64 + r] = d.y;
            xT[2 * 64 + r] = d.z;
        }
        for (int q = 0; q < 4; q++) {
            int j = h * 4 + q;
            float4 v = prow[j];
            int k = 3 + j * 4;
            xT[(k + 0) * 64 + r] = v.x;
            xT[(k + 1) * 64 + r] = v.y;
            xT[(k + 2) * 64 + r] = v.z;
            xT[(k + 3) * 64 + r] = v.w;
        }
    }
    __syncthreads();

    int ty = tid >> 4;              // 4 rows each
    int tx = tid & 15;              // 4 cols each
    float acc[4][4];
    #pragma unroll
    for (int i = 0; i < 4; i++)
        #pragma unroll
        for (int j = 0; j < 4; j++) acc[i][j] = sB[tx * 4 + j];

    for (int k = 0; k < 67; k++) {
        const float* xk = &xT[k * 64 + ty * 4];
        const float* wk = &sW[k * 64 + tx * 4];
        float w0 = wk[0], w1v = wk[1], w2v = wk[2], w3v = wk[3];
        #pragma unroll
        for (int i = 0; i < 4; i++) {
            float xv = xk[i];
            acc[i][0] += xv * w0;
            acc[i][1] += xv * w1v;
            acc[i][2] += xv * w2v;
            acc[i][3] += xv * w3v;
        }
    }

    float s[4] = {0.f, 0.f, 0.f, 0.f};
    float q[4] = {0.f, 0.f, 0.f, 0.f};
    #pragma unroll
    for (int i = 0; i < 4; i++) {
        int row = R0 + ty * 4 + i;
        z1[static_cast<size_t>(row) * 16 + tx] =
            make_float4(acc[i][0], acc[i][1], acc[i][2], acc[i][3]);
        #pragma unroll
        for (int j = 0; j < 4; j++) {
            s[j] += acc[i][j];
            q[j] += acc[i][j] * acc[i][j];
        }
    }
    int lane = tid & 63;
    #pragma unroll
    for (int j = 0; j < 4; j++) {
        s[j] += __shfl_xor(s[j], 16); q[j] += __shfl_xor(q[j], 16);
        s[j] += __shfl_xor(s[j], 32); q[j] += __shfl_xor(q[j], 32);
    }
    if (lane < 16) {
        #pragma unroll
        for (int j = 0; j < 4; j++) {
            atomicAdd(&sStat[tx * 4 + j],      s[j]);
            atomicAdd(&sStat[64 + tx * 4 + j], q[j]);
        }
    }
    __syncthreads();
    if (tid < 128) {
        atomicAdd(&stats[tid], sStat[tid]);
    }
}

// ---------------------------------------------------------------- layer 2
// 64 rows x 64 cols; BN1+ReLU applied while staging; fused stats.
__global__ __launch_bounds__(256) void ssaLayer2Kernel(
    const float4* z1, const float* w2, const float* bias2,
    const float* gamma1, const float* beta1, const float* statsIn,
    float4* z2, float* statsOut)
{
    __shared__ float xT[64 * 64];     // 16 KB
    __shared__ float sW[64 * 64];     // 16 KB
    __shared__ float sB[64];
    __shared__ float sG[64];
    __shared__ float sH[64];
    __shared__ float sStat[128];
    int tid = static_cast<int>(threadIdx.x);
    int R0  = static_cast<int>(blockIdx.x) * 64;

    for (int i = tid; i < 64 * 64; i += 256) {
        int k = i >> 6;
        int c = i & 63;
        sW[i] = w2[c * 64 + k];
    }
    if (tid < 64) {
        sB[tid] = bias2[tid];
        double mean = static_cast<double>(statsIn[tid]) / static_cast<double>(kNRows);
        double var  = static_cast<double>(statsIn[64 + tid]) / static_cast<double>(kNRows) - mean * mean;
        double rstd = 1.0 / sqrt(var + 1e-5);
        float g = static_cast<float>(rstd) * gamma1[tid];
        sG[tid] = g;
        sH[tid] = beta1[tid] - static_cast<float>(mean) * g;
    }
    if (tid < 128) sStat[tid] = 0.0f;
    __syncthreads();

    {
        int r = tid & 63;
        int h = tid >> 6;
        const float4* zr = z1 + static_cast<size_t>(R0 + r) * 16;
        for (int q = 0; q < 4; q++) {
            int j = h * 4 + q;
            float4 v = zr[j];
            int k = j * 4;
            xT[(k + 0) * 64 + r] = fmaxf(v.x * sG[k + 0] + sH[k + 0], 0.0f);
            xT[(k + 1) * 64 + r] = fmaxf(v.y * sG[k + 1] + sH[k + 1], 0.0f);
            xT[(k + 2) * 64 + r] = fmaxf(v.z * sG[k + 2] + sH[k + 2], 0.0f);
            xT[(k + 3) * 64 + r] = fmaxf(v.w * sG[k + 3] + sH[k + 3], 0.0f);
        }
    }
    __syncthreads();

    int ty = tid >> 4;
    int tx = tid & 15;
    float acc[4][4];
    #pragma unroll
    for (int i = 0; i < 4; i++)
        #pragma unroll
        for (int j = 0; j < 4; j++) acc[i][j] = sB[tx * 4 + j];

    for (int k = 0; k < 64; k++) {
        const float* xk = &xT[k * 64 + ty * 4];
        const float* wk = &sW[k * 64 + tx * 4];
        float w0 = wk[0], w1v = wk[1], w2v = wk[2], w3v = wk[3];
        #pragma unroll
        for (int i = 0; i < 4; i++) {
            float xv = xk[i];
            acc[i][0] += xv * w0;
            acc[i][1] += xv * w1v;
            acc[i][2] += xv * w2v;
            acc[i][3] += xv * w3v;
        }
    }

    float s[4] = {0.f, 0.f, 0.f, 0.f};
    float q[4] = {0.f, 0.f, 0.f, 0.f};
    #pragma unroll
    for (int i = 0; i < 4; i++) {
        int row = R0 + ty * 4 + i;
        z2[static_cast<size_t>(row) * 16 + tx] =
            make_float4(acc[i][0], acc[i][1], acc[i][2], acc[i][3]);
        #pragma unroll
        for (int j = 0; j < 4; j++) {
            s[j] += acc[i][j];
            q[j] += acc[i][j] * acc[i][j];
        }
    }
    int lane = tid & 63;
    #pragma unroll
    for (int j = 0; j < 4; j++) {
        s[j] += __shfl_xor(s[j], 16); q[j] += __shfl_xor(q[j], 16);
        s[j] += __shfl_xor(s[j], 32); q[j] += __shfl_xor(q[j], 32);
    }
    if (lane < 16) {
        #pragma unroll
        for (int j = 0; j < 4; j++) {
            atomicAdd(&sStat[tx * 4 + j],      s[j]);
            atomicAdd(&sStat[64 + tx * 4 + j], q[j]);
        }
    }
    __syncthreads();
    if (tid < 128) {
        atomicAdd(&statsOut[tid], sStat[tid]);
    }
}

// ---------------------------------------------------------------- layer 3
// 64 rows x 128 cols; BN2+ReLU on staging; 2 groups per block; two-stage
// pre-BN max-pool (wave shuffle -> sPool combine); fused BN3 stats.
__global__ __launch_bounds__(256) void ssaLayer3Kernel(
    const float4* z2, const float* w3, const float* bias3,
    const float* gamma2, const float* beta2, const float* statsIn,
    float* poolMax, float* statsOut)
{
    __shared__ float xT[64 * 64];     // 16 KB
    __shared__ float sW[64 * 128];    // 32 KB
    __shared__ float sB[128];
    __shared__ float sG[64];
    __shared__ float sH[64];
    __shared__ float sStat[256];
    __shared__ float sPool[4 * 128];  // wave partial maxima
    int tid = static_cast<int>(threadIdx.x);
    int R0  = static_cast<int>(blockIdx.x) * 64;

    for (int i = tid; i < 64 * 128; i += 256) {
        int k = i >> 7;
        int c = i & 127;
        sW[i] = w3[c * 64 + k];
    }
    if (tid < 64) {
        double mean = static_cast<double>(statsIn[tid]) / static_cast<double>(kNRows);
        double var  = static_cast<double>(statsIn[64 + tid]) / static_cast<double>(kNRows) - mean * mean;
        double rstd = 1.0 / sqrt(var + 1e-5);
        float g = static_cast<float>(rstd) * gamma2[tid];
        sG[tid] = g;
        sH[tid] = beta2[tid] - static_cast<float>(mean) * g;
    }
    if (tid < 128) sB[tid] = bias3[tid];
    if (tid < 256) sStat[tid] = 0.0f;
    __syncthreads();

    {
        int r = tid & 63;
        int h = tid >> 6;
        const float4* zr = z2 + static_cast<size_t>(R0 + r) * 16;
        for (int q = 0; q < 4; q++) {
            int j = h * 4 + q;
            float4 v = zr[j];
            int k = j * 4;
            xT[(k + 0) * 64 + r] = fmaxf(v.x * sG[k + 0] + sH[k + 0], 0.0f);
            xT[(k + 1) * 64 + r] = fmaxf(v.y * sG[k + 1] + sH[k + 1], 0.0f);
            xT[(k + 2) * 64 + r] = fmaxf(v.z * sG[k + 2] + sH[k + 2], 0.0f);
            xT[(k + 3) * 64 + r] = fmaxf(v.w * sG[k + 3] + sH[k + 3], 0.0f);
        }
    }
    __syncthreads();

    int ty = tid >> 4;              // rows ty*4..ty*4+3; wave wv = ty>>2
    int tx = tid & 15;              // cols tx*8..tx*8+7
    float acc[4][8];
    #pragma unroll
    for (int i = 0; i < 4; i++)
        #pragma unroll
        for (int j = 0; j < 8; j++) acc[i][j] = sB[tx * 8 + j];

    for (int k = 0; k < 64; k++) {
        const float* xk = &xT[k * 64 + ty * 4];
        const float* wk = &sW[k * 128 + tx * 8];
        float wv0[8];
        #pragma unroll
        for (int j = 0; j < 8; j++) wv0[j] = wk[j];
        #pragma unroll
        for (int i = 0; i < 4; i++) {
            float xv = xk[i];
            #pragma unroll
            for (int j = 0; j < 8; j++) {
                acc[i][j] += xv * wv0[j];
            }
        }
    }

    int lane = tid & 63;
    int wv   = tid >> 6;            // wave id, rows [wv*16, wv*16+16)
    float mx[8];
    float s[8];
    float q[8];
    #pragma unroll
    for (int j = 0; j < 8; j++) {
        mx[j] = acc[0][j];
        s[j]  = 0.0f;
        q[j]  = 0.0f;
    }
    #pragma unroll
    for (int i = 0; i < 4; i++)
        #pragma unroll
        for (int j = 0; j < 8; j++) {
            float v = acc[i][j];
            mx[j] = fmaxf(mx[j], v);
            s[j] += v;
            q[j] += v * v;
        }
    #pragma unroll
    for (int j = 0; j < 8; j++) {
        mx[j] = fmaxf(mx[j], __shfl_xor(mx[j], 16));
        mx[j] = fmaxf(mx[j], __shfl_xor(mx[j], 32));
        s[j] += __shfl_xor(s[j], 16); q[j] += __shfl_xor(q[j], 16);
        s[j] += __shfl_xor(s[j], 32); q[j] += __shfl_xor(q[j], 32);
    }
    if (lane < 16) {
        #pragma unroll
        for (int j = 0; j < 8; j++) {
            sPool[wv * 128 + tx * 8 + j] = mx[j];
            atomicAdd(&sStat[tx * 8 + j],       s[j]);
            atomicAdd(&sStat[128 + tx * 8 + j], q[j]);
        }
    }
    __syncthreads();

    // combine wave pairs -> per-group max; coalesced pool write [grp][ch]
    {
        int c = tid & 127;
        int g = tid >> 7;           // 0..1
        float m = fmaxf(sPool[(2 * g) * 128 + c], sPool[(2 * g + 1) * 128 + c]);
        poolMax[static_cast<size_t>(static_cast<int>(blockIdx.x) * 2 + g) * kC3 + c] = m;
    }
    if (tid < 256) {
        atomicAdd(&statsOut[tid], sStat[tid]);
    }
}

// ---------------------------------------------------------------- finalize
__global__ __launch_bounds__(256) void ssaFinalKernel(
    const float* poolMax, const float* sum3, const float* sq3,
    const float* gamma3, const float* beta3, float* outTail)
{
    __shared__ float sG[128];
    __shared__ float sH[128];
    int tid = static_cast<int>(threadIdx.x);
    if (tid < 128) {
        double mean = static_cast<double>(sum3[tid]) / static_cast<double>(kNRows);
        double var  = static_cast<double>(sq3[tid]) / static_cast<double>(kNRows) - mean * mean;
        double rstd = 1.0 / sqrt(var + 1e-5);
        float g = static_cast<float>(rstd) * gamma3[tid];
        sG[tid] = g;
        sH[tid] = beta3[tid] - static_cast<float>(mean) * g;
    }
    __syncthreads();
    int e  = static_cast<int>(blockIdx.x) * 256 + tid;
    int b  = e >> 18;
    int ch = (e >> 11) & 127;
    int s  = e & 2047;
    size_t gi = static_cast<size_t>(b * kNS + s) * kC3 + ch;
    outTail[e] = fmaxf(poolMax[gi] * sG[ch] + sH[ch], 0.0f);
}

// ---------------------------------------------------------------- launch
static inline void* ssaWsAt(void* base, size_t byteOff)
{
    return static_cast<void*>(static_cast<char*>(base) + byteOff);
}

extern "C" __attribute__((visibility("default"), used))
void kernel_launch(void* const* d_in, const int* in_sizes, int n_in,
                   void* d_out, int out_size, void* d_ws, size_t ws_size,
                   hipStream_t stream)
{
    static_cast<void>(in_sizes);
    static_cast<void>(n_in);
    static_cast<void>(out_size);
    static_cast<void>(ws_size);

    const float*  xyz    = static_cast<const float*>(d_in[0]);
    const float4* points = static_cast<const float4*>(d_in[1]);
    const float*  newXyz = static_cast<const float*>(d_in[2]);
    const float*  w1Ptr  = static_cast<const float*>(d_in[3]);
    const float*  b1Ptr  = static_cast<const float*>(d_in[4]);
    const float*  g1Ptr  = static_cast<const float*>(d_in[5]);
    const float*  e1Ptr  = static_cast<const float*>(d_in[6]);
    const float*  w2Ptr  = static_cast<const float*>(d_in[7]);
    const float*  b2Ptr  = static_cast<const float*>(d_in[8]);
    const float*  g2Ptr  = static_cast<const float*>(d_in[9]);
    const float*  e2Ptr  = static_cast<const float*>(d_in[10]);
    const float*  w3Ptr  = static_cast<const float*>(d_in[11]);
    const float*  b3Ptr  = static_cast<const float*>(d_in[12]);
    const float*  g3Ptr  = static_cast<const float*>(d_in[13]);
    const float*  e3Ptr  = static_cast<const float*>(d_in[14]);

    float4* soa   = static_cast<float4*>(ssaWsAt(d_ws, 0));           //   1,048,576 B
    int*    bIdx  = static_cast<int*>(ssaWsAt(d_ws, 1048576));        //   1,048,576 B
    float4* bDxy  = static_cast<float4*>(ssaWsAt(d_ws, 2097152));     //   4,194,304 B
    float4* z1    = static_cast<float4*>(ssaWsAt(d_ws, 6291456));     //  67,108,864 B
    float4* z2    = static_cast<float4*>(ssaWsAt(d_ws, 73400320));    //  67,108,864 B
    float*  pMax  = static_cast<float*>(ssaWsAt(d_ws, 140509184));    //   4,194,304 B
    float*  stats = static_cast<float*>(ssaWsAt(d_ws, 144703488));    //   2,048 B
    float*  outF  = static_cast<float*>(d_out);

    ssaPrepKernel<<<256, 256, 0, stream>>>(xyz, newXyz, outF, soa, stats);
    ssaBallKernel<<<kNGrp / 4, 256, 0, stream>>>(newXyz, soa, bIdx, bDxy);
    ssaLayer1Kernel<<<kNRows / 64, 256, 0, stream>>>(points, w1Ptr, b1Ptr, bIdx, bDxy,
                                                     z1, stats);
    ssaLayer2Kernel<<<kNRows / 64, 256, 0, stream>>>(z1, w2Ptr, b2Ptr, g1Ptr, e1Ptr,
                                                     stats, z2, stats + 128);
    ssaLayer3Kernel<<<kNRows / 64, 256, 0, stream>>>(z2, w3Ptr, b3Ptr, g2Ptr, e2Ptr,
                                                     stats + 128, pMax, stats + 256);
    ssaFinalKernel<<<kNB * kC3 * kNS / 256, 256, 0, stream>>>(pMax, stats + 256, stats + 384,
                                                              g3Ptr, e3Ptr,
                                                              outF + kNB * kNS * 3);
}

// Round 22
// 351.549 us; speedup vs baseline: 1.4592x; 1.4592x over previous
//
#include <hip/hip_runtime.h>

// SingleScaleSA: B=4, N=16384, S=2048, K=32, mlp 64 -> 64 -> 128, radius 0.2.
// FP32 I/O. Round 22: round-19 tile shape (128 rows, 8-wide thread tiles)
// with ONLY the xT activation buffer K-chunked (2x32) inside a #pragma
// unroll 1 loop (prevents the r20 VGPR blowup). LDS: L1 ~35.5K, L2 ~33K
// (4 blocks/CU), L3 ~50K (3 blocks/CU).
constexpr int kNB    = 4;
constexpr int kNPts  = 16384;
constexpr int kNS    = 2048;
constexpr int kNK    = 32;
constexpr int kC3    = 128;
constexpr int kNRows = kNB * kNS * kNK;   // 262144
constexpr int kNGrp  = kNB * kNS;         // 8192
constexpr double kR2 = 0.2 * 0.2;

// ---------------------------------------------------------------- prep
__global__ __launch_bounds__(256) void ssaPrepKernel(
    const float* xyz, const float* newXyz,
    float* outHead, float4* soa, float* stats)
{
    int t = static_cast<int>(blockIdx.x) * 256 + static_cast<int>(threadIdx.x);
    if (t < kNB * kNPts) {
        soa[t] = make_float4(xyz[t * 3 + 0], xyz[t * 3 + 1], xyz[t * 3 + 2], 0.0f);
    }
    if (t < kNB * kNS * 3) {
        outHead[t] = newXyz[t];
    }
    if (t < 512) {
        stats[t] = 0.0f;
    }
}

// ---------------------------------------------------------------- ball query
__global__ __launch_bounds__(256) void ssaBallKernel(
    const float* newXyz, const float4* soa,
    int* ballIdx, float4* ballDxyz)
{
    int tid  = static_cast<int>(threadIdx.x);
    int w    = (static_cast<int>(blockIdx.x) * 256 + tid) >> 6;
    int lane = tid & 63;
    int b    = w >> 11;
    float qx = newXyz[w * 3 + 0];
    float qy = newXyz[w * 3 + 1];
    float qz = newXyz[w * 3 + 2];
    double qxd = static_cast<double>(qx);
    double qyd = static_cast<double>(qy);
    double qzd = static_cast<double>(qz);
    double qq  = qxd * qxd + qyd * qyd + qzd * qzd;
    const float4* sp = soa + b * kNPts;
    int*    oi = ballIdx  + static_cast<size_t>(w) * kNK;
    float4* od = ballDxyz + static_cast<size_t>(w) * kNK;

    int cnt = 0;
    int firstN = -1;
    float fdx = 0.0f, fdy = 0.0f, fdz = 0.0f;
    for (int base = 0; base < kNPts && cnt < kNK; base += 64) {
        float4 p = sp[base + lane];
        double pxd = static_cast<double>(p.x);
        double pyd = static_cast<double>(p.y);
        double pzd = static_cast<double>(p.z);
        double d2  = qq + (pxd * pxd + pyd * pyd + pzd * pzd)
                   - 2.0 * (qxd * pxd + qyd * pyd + qzd * pzd);
        bool hit   = (d2 <= kR2);
        unsigned long long m = __ballot(hit);
        int pos = cnt + __popcll(m & ((1ull << lane) - 1ull));
        if (hit && pos < kNK) {
            float dx = p.x - qx;
            float dy = p.y - qy;
            float dz = p.z - qz;
            oi[pos] = base + lane;
            od[pos] = make_float4(dx, dy, dz, 0.0f);
            if (pos == 0) { firstN = base + lane; fdx = dx; fdy = dy; fdz = dz; }
        }
        cnt += __popcll(m);
    }
    if (cnt < kNK) {
        unsigned long long hv = __ballot(firstN >= 0);
        int fi;
        float dx, dy, dz;
        if (hv != 0ull) {
            int src = __builtin_ctzll(hv);
            fi = __shfl(firstN, src);
            dx = __shfl(fdx, src);
            dy = __shfl(fdy, src);
            dz = __shfl(fdz, src);
        } else {
            float4 p = sp[kNPts - 1];
            fi = kNPts - 1;
            dx = p.x - qx;
            dy = p.y - qy;
            dz = p.z - qz;
        }
        for (int p2 = cnt + lane; p2 < kNK; p2 += 64) {
            oi[p2] = fi;
            od[p2] = make_float4(dx, dy, dz, 0.0f);
        }
    }
}

// ---------------------------------------------------------------- layer 1
// 128 rows x 64 cols; dxyz in persistent sXyz strip; 64 point-dims staged in
// 2x32 xT chunks (#pragma unroll 1). Fused stats -> stats[0..63]+, [64..127].
__global__ __launch_bounds__(256) void ssaLayer1Kernel(
    const float4* points, const float* w1, const float* bias1,
    const int* ballIdx, const float4* ballDxyz, float4* z1, float* stats)
{
    __shared__ float sXyz[3 * 128];   // 1.5 KB
    __shared__ float xT[32 * 128];    // 16 KB
    __shared__ float sW[67 * 64];     // ~17.2 KB
    __shared__ float sB[64];
    __shared__ float sStat[128];
    int tid = static_cast<int>(threadIdx.x);
    int R0  = static_cast<int>(blockIdx.x) * 128;
    int ty  = tid >> 4;
    int tx  = tid & 15;
    int r   = tid & 127;
    int h   = tid >> 7;

    for (int i = tid; i < 67 * 64; i += 256) {
        int k = i >> 6;
        int c = i & 63;
        sW[i] = w1[c * 67 + k];
    }
    if (tid < 64)  sB[tid] = bias1[tid];
    if (tid < 128) sStat[tid] = 0.0f;

    int gi = ballIdx[R0 + r];
    int b  = (R0 + r) >> 16;
    const float4* prow = points + (static_cast<size_t>(b) * kNPts + static_cast<size_t>(gi)) * 16;
    if (h == 0) {
        float4 d = ballDxyz[R0 + r];
        sXyz[0 * 128 + r] = d.x;
        sXyz[1 * 128 + r] = d.y;
        sXyz[2 * 128 + r] = d.z;
    }
    __syncthreads();

    float acc[8][4];
    #pragma unroll
    for (int i = 0; i < 8; i++)
        #pragma unroll
        for (int j = 0; j < 4; j++) acc[i][j] = sB[tx * 4 + j];

    // dxyz contribution (k = 0..2)
    #pragma unroll
    for (int k = 0; k < 3; k++) {
        const float* xk = &sXyz[k * 128 + ty * 8];
        const float* wk = &sW[k * 64 + tx * 4];
        float w0 = wk[0], w1v = wk[1], w2v = wk[2], w3v = wk[3];
        #pragma unroll
        for (int i = 0; i < 8; i++) {
            float xv = xk[i];
            acc[i][0] += xv * w0;
            acc[i][1] += xv * w1v;
            acc[i][2] += xv * w2v;
            acc[i][3] += xv * w3v;
        }
    }

    #pragma unroll 1
    for (int ch = 0; ch < 2; ch++) {
        if (ch > 0) __syncthreads();
        // stage point dims [ch*32, ch*32+32) transposed
        for (int j = h * 4; j < h * 4 + 4; j++) {
            float4 v = prow[ch * 8 + j];
            int k = j * 4;
            xT[(k + 0) * 128 + r] = v.x;
            xT[(k + 1) * 128 + r] = v.y;
            xT[(k + 2) * 128 + r] = v.z;
            xT[(k + 3) * 128 + r] = v.w;
        }
        __syncthreads();

        int kw = 3 + ch * 32;
        for (int k = 0; k < 32; k++) {
            const float* xk = &xT[k * 128 + ty * 8];
            const float* wk = &sW[(kw + k) * 64 + tx * 4];
            float w0 = wk[0], w1v = wk[1], w2v = wk[2], w3v = wk[3];
            #pragma unroll
            for (int i = 0; i < 8; i++) {
                float xv = xk[i];
                acc[i][0] += xv * w0;
                acc[i][1] += xv * w1v;
                acc[i][2] += xv * w2v;
                acc[i][3] += xv * w3v;
            }
        }
    }

    float s[4] = {0.f, 0.f, 0.f, 0.f};
    float q[4] = {0.f, 0.f, 0.f, 0.f};
    #pragma unroll
    for (int i = 0; i < 8; i++) {
        int row = R0 + ty * 8 + i;
        z1[static_cast<size_t>(row) * 16 + tx] =
            make_float4(acc[i][0], acc[i][1], acc[i][2], acc[i][3]);
        #pragma unroll
        for (int j = 0; j < 4; j++) {
            s[j] += acc[i][j];
            q[j] += acc[i][j] * acc[i][j];
        }
    }
    int lane = tid & 63;
    #pragma unroll
    for (int j = 0; j < 4; j++) {
        s[j] += __shfl_xor(s[j], 16); q[j] += __shfl_xor(q[j], 16);
        s[j] += __shfl_xor(s[j], 32); q[j] += __shfl_xor(q[j], 32);
    }
    if (lane < 16) {
        #pragma unroll
        for (int j = 0; j < 4; j++) {
            atomicAdd(&sStat[tx * 4 + j],      s[j]);
            atomicAdd(&sStat[64 + tx * 4 + j], q[j]);
        }
    }
    __syncthreads();
    if (tid < 128) {
        atomicAdd(&stats[tid], sStat[tid]);
    }
}

// ---------------------------------------------------------------- layer 2
// 128 rows x 64 cols; BN1+ReLU while staging; xT chunked 2x32 (unroll 1).
__global__ __launch_bounds__(256) void ssaLayer2Kernel(
    const float4* z1, const float* w2, const float* bias2,
    const float* gamma1, const float* beta1, const float* statsIn,
    float4* z2, float* statsOut)
{
    __shared__ float xT[32 * 128];    // 16 KB
    __shared__ float sW[64 * 64];     // 16 KB
    __shared__ float sB[64];
    __shared__ float sG[64];
    __shared__ float sH[64];
    __shared__ float sStat[128];
    int tid = static_cast<int>(threadIdx.x);
    int R0  = static_cast<int>(blockIdx.x) * 128;
    int ty  = tid >> 4;
    int tx  = tid & 15;
    int r   = tid & 127;
    int h   = tid >> 7;

    for (int i = tid; i < 64 * 64; i += 256) {
        int k = i >> 6;
        int c = i & 63;
        sW[i] = w2[c * 64 + k];
    }
    if (tid < 64) {
        sB[tid] = bias2[tid];
        double mean = static_cast<double>(statsIn[tid]) / static_cast<double>(kNRows);
        double var  = static_cast<double>(statsIn[64 + tid]) / static_cast<double>(kNRows) - mean * mean;
        double rstd = 1.0 / sqrt(var + 1e-5);
        float g = static_cast<float>(rstd) * gamma1[tid];
        sG[tid] = g;
        sH[tid] = beta1[tid] - static_cast<float>(mean) * g;
    }
    if (tid < 128) sStat[tid] = 0.0f;
    __syncthreads();

    float acc[8][4];
    #pragma unroll
    for (int i = 0; i < 8; i++)
        #pragma unroll
        for (int j = 0; j < 4; j++) acc[i][j] = sB[tx * 4 + j];

    const float4* zr = z1 + static_cast<size_t>(R0 + r) * 16;

    #pragma unroll 1
    for (int ch = 0; ch < 2; ch++) {
        if (ch > 0) __syncthreads();
        for (int j = h * 4; j < h * 4 + 4; j++) {
            float4 v = zr[ch * 8 + j];
            int kg = ch * 32 + j * 4;
            int k  = j * 4;
            xT[(k + 0) * 128 + r] = fmaxf(v.x * sG[kg + 0] + sH[kg + 0], 0.0f);
            xT[(k + 1) * 128 + r] = fmaxf(v.y * sG[kg + 1] + sH[kg + 1], 0.0f);
            xT[(k + 2) * 128 + r] = fmaxf(v.z * sG[kg + 2] + sH[kg + 2], 0.0f);
            xT[(k + 3) * 128 + r] = fmaxf(v.w * sG[kg + 3] + sH[kg + 3], 0.0f);
        }
        __syncthreads();

        int kw = ch * 32;
        for (int k = 0; k < 32; k++) {
            const float* xk = &xT[k * 128 + ty * 8];
            const float* wk = &sW[(kw + k) * 64 + tx * 4];
            float w0 = wk[0], w1v = wk[1], w2v = wk[2], w3v = wk[3];
            #pragma unroll
            for (int i = 0; i < 8; i++) {
                float xv = xk[i];
                acc[i][0] += xv * w0;
                acc[i][1] += xv * w1v;
                acc[i][2] += xv * w2v;
                acc[i][3] += xv * w3v;
            }
        }
    }

    float s[4] = {0.f, 0.f, 0.f, 0.f};
    float q[4] = {0.f, 0.f, 0.f, 0.f};
    #pragma unroll
    for (int i = 0; i < 8; i++) {
        int row = R0 + ty * 8 + i;
        z2[static_cast<size_t>(row) * 16 + tx] =
            make_float4(acc[i][0], acc[i][1], acc[i][2], acc[i][3]);
        #pragma unroll
        for (int j = 0; j < 4; j++) {
            s[j] += acc[i][j];
            q[j] += acc[i][j] * acc[i][j];
        }
    }
    int lane = tid & 63;
    #pragma unroll
    for (int j = 0; j < 4; j++) {
        s[j] += __shfl_xor(s[j], 16); q[j] += __shfl_xor(q[j], 16);
        s[j] += __shfl_xor(s[j], 32); q[j] += __shfl_xor(q[j], 32);
    }
    if (lane < 16) {
        #pragma unroll
        for (int j = 0; j < 4; j++) {
            atomicAdd(&sStat[tx * 4 + j],      s[j]);
            atomicAdd(&sStat[64 + tx * 4 + j], q[j]);
        }
    }
    __syncthreads();
    if (tid < 128) {
        atomicAdd(&statsOut[tid], sStat[tid]);
    }
}

// ---------------------------------------------------------------- layer 3
// 128 rows x 128 cols; xT chunked 2x32 (unroll 1); pre-BN wave max-pool
// (wave g owns group g's 32 rows); fused BN3 stats.
__global__ __launch_bounds__(256) void ssaLayer3Kernel(
    const float4* z2, const float* w3, const float* bias3,
    const float* gamma2, const float* beta2, const float* statsIn,
    float* poolMax, float* statsOut)
{
    __shared__ float xT[32 * 128];    // 16 KB
    __shared__ float sW[64 * 128];    // 32 KB
    __shared__ float sB[128];
    __shared__ float sG[64];
    __shared__ float sH[64];
    __shared__ float sStat[256];
    int tid = static_cast<int>(threadIdx.x);
    int R0  = static_cast<int>(blockIdx.x) * 128;
    int ty  = tid >> 4;
    int tx  = tid & 15;
    int r   = tid & 127;
    int h   = tid >> 7;

    for (int i = tid; i < 64 * 128; i += 256) {
        int k = i >> 7;
        int c = i & 127;
        sW[i] = w3[c * 64 + k];
    }
    if (tid < 64) {
        double mean = static_cast<double>(statsIn[tid]) / static_cast<double>(kNRows);
        double var  = static_cast<double>(statsIn[64 + tid]) / static_cast<double>(kNRows) - mean * mean;
        double rstd = 1.0 / sqrt(var + 1e-5);
        float g = static_cast<float>(rstd) * gamma2[tid];
        sG[tid] = g;
        sH[tid] = beta2[tid] - static_cast<float>(mean) * g;
    }
    if (tid < 128) sB[tid] = bias3[tid];
    if (tid < 256) sStat[tid] = 0.0f;
    __syncthreads();

    float acc[8][8];
    #pragma unroll
    for (int i = 0; i < 8; i++)
        #pragma unroll
        for (int j = 0; j < 8; j++) acc[i][j] = sB[tx * 8 + j];

    const float4* zr = z2 + static_cast<size_t>(R0 + r) * 16;

    #pragma unroll 1
    for (int ch = 0; ch < 2; ch++) {
        if (ch > 0) __syncthreads();
        for (int j = h * 4; j < h * 4 + 4; j++) {
            float4 v = zr[ch * 8 + j];
            int kg = ch * 32 + j * 4;
            int k  = j * 4;
            xT[(k + 0) * 128 + r] = fmaxf(v.x * sG[kg + 0] + sH[kg + 0], 0.0f);
            xT[(k + 1) * 128 + r] = fmaxf(v.y * sG[kg + 1] + sH[kg + 1], 0.0f);
            xT[(k + 2) * 128 + r] = fmaxf(v.z * sG[kg + 2] + sH[kg + 2], 0.0f);
            xT[(k + 3) * 128 + r] = fmaxf(v.w * sG[kg + 3] + sH[kg + 3], 0.0f);
        }
        __syncthreads();

        int kw = ch * 32;
        for (int k = 0; k < 32; k++) {
            const float* xk = &xT[k * 128 + ty * 8];
            const float* wk = &sW[(kw + k) * 128 + tx * 8];
            float wv[8];
            #pragma unroll
            for (int j = 0; j < 8; j++) wv[j] = wk[j];
            #pragma unroll
            for (int i = 0; i < 8; i++) {
                float xv = xk[i];
                #pragma unroll
                for (int j = 0; j < 8; j++) {
                    acc[i][j] += xv * wv[j];
                }
            }
        }
    }

    // pooling (max over the wave's 32 rows) + stats
    int lane = tid & 63;
    int grp  = static_cast<int>(blockIdx.x) * 4 + (ty >> 2);
    float mx[8];
    float s[8];
    float q[8];
    #pragma unroll
    for (int j = 0; j < 8; j++) {
        mx[j] = acc[0][j];
        s[j]  = 0.0f;
        q[j]  = 0.0f;
    }
    #pragma unroll
    for (int i = 0; i < 8; i++)
        #pragma unroll
        for (int j = 0; j < 8; j++) {
            float v = acc[i][j];
            mx[j] = fmaxf(mx[j], v);
            s[j] += v;
            q[j] += v * v;
        }
    #pragma unroll
    for (int j = 0; j < 8; j++) {
        mx[j] = fmaxf(mx[j], __shfl_xor(mx[j], 16));
        mx[j] = fmaxf(mx[j], __shfl_xor(mx[j], 32));
        s[j] += __shfl_xor(s[j], 16); q[j] += __shfl_xor(q[j], 16);
        s[j] += __shfl_xor(s[j], 32); q[j] += __shfl_xor(q[j], 32);
    }
    if (lane < 16) {
        #pragma unroll
        for (int j = 0; j < 8; j++) {
            poolMax[static_cast<size_t>(grp) * kC3 + tx * 8 + j] = mx[j];
            atomicAdd(&sStat[tx * 8 + j],       s[j]);
            atomicAdd(&sStat[128 + tx * 8 + j], q[j]);
        }
    }
    __syncthreads();
    if (tid < 256) {
        atomicAdd(&statsOut[tid], sStat[tid]);
    }
}

// ---------------------------------------------------------------- finalize
__global__ __launch_bounds__(256) void ssaFinalKernel(
    const float* poolMax, const float* sum3, const float* sq3,
    const float* gamma3, const float* beta3, float* outTail)
{
    __shared__ float sG[128];
    __shared__ float sH[128];
    int tid = static_cast<int>(threadIdx.x);
    if (tid < 128) {
        double mean = static_cast<double>(sum3[tid]) / static_cast<double>(kNRows);
        double var  = static_cast<double>(sq3[tid]) / static_cast<double>(kNRows) - mean * mean;
        double rstd = 1.0 / sqrt(var + 1e-5);
        float g = static_cast<float>(rstd) * gamma3[tid];
        sG[tid] = g;
        sH[tid] = beta3[tid] - static_cast<float>(mean) * g;
    }
    __syncthreads();
    int e  = static_cast<int>(blockIdx.x) * 256 + tid;
    int b  = e >> 18;
    int ch = (e >> 11) & 127;
    int s  = e & 2047;
    size_t gi = static_cast<size_t>(b * kNS + s) * kC3 + ch;
    outTail[e] = fmaxf(poolMax[gi] * sG[ch] + sH[ch], 0.0f);
}

// ---------------------------------------------------------------- launch
static inline void* ssaWsAt(void* base, size_t byteOff)
{
    return static_cast<void*>(static_cast<char*>(base) + byteOff);
}

extern "C" __attribute__((visibility("default"), used))
void kernel_launch(void* const* d_in, const int* in_sizes, int n_in,
                   void* d_out, int out_size, void* d_ws, size_t ws_size,
                   hipStream_t stream)
{
    static_cast<void>(in_sizes);
    static_cast<void>(n_in);
    static_cast<void>(out_size);
    static_cast<void>(ws_size);

    const float*  xyz    = static_cast<const float*>(d_in[0]);
    const float4* points = static_cast<const float4*>(d_in[1]);
    const float*  newXyz = static_cast<const float*>(d_in[2]);
    const float*  w1Ptr  = static_cast<const float*>(d_in[3]);
    const float*  b1Ptr  = static_cast<const float*>(d_in[4]);
    const float*  g1Ptr  = static_cast<const float*>(d_in[5]);
    const float*  e1Ptr  = static_cast<const float*>(d_in[6]);
    const float*  w2Ptr  = static_cast<const float*>(d_in[7]);
    const float*  b2Ptr  = static_cast<const float*>(d_in[8]);
    const float*  g2Ptr  = static_cast<const float*>(d_in[9]);
    const float*  e2Ptr  = static_cast<const float*>(d_in[10]);
    const float*  w3Ptr  = static_cast<const float*>(d_in[11]);
    const float*  b3Ptr  = static_cast<const float*>(d_in[12]);
    const float*  g3Ptr  = static_cast<const float*>(d_in[13]);
    const float*  e3Ptr  = static_cast<const float*>(d_in[14]);

    float4* soa   = static_cast<float4*>(ssaWsAt(d_ws, 0));           //   1,048,576 B
    int*    bIdx  = static_cast<int*>(ssaWsAt(d_ws, 1048576));        //   1,048,576 B
    float4* bDxy  = static_cast<float4*>(ssaWsAt(d_ws, 2097152));     //   4,194,304 B
    float4* z1    = static_cast<float4*>(ssaWsAt(d_ws, 6291456));     //  67,108,864 B
    float4* z2    = static_cast<float4*>(ssaWsAt(d_ws, 73400320));    //  67,108,864 B
    float*  pMax  = static_cast<float*>(ssaWsAt(d_ws, 140509184));    //   4,194,304 B
    float*  stats = static_cast<float*>(ssaWsAt(d_ws, 144703488));    //   2,048 B
    float*  outF  = static_cast<float*>(d_out);

    ssaPrepKernel<<<256, 256, 0, stream>>>(xyz, newXyz, outF, soa, stats);
    ssaBallKernel<<<kNGrp / 4, 256, 0, stream>>>(newXyz, soa, bIdx, bDxy);
    ssaLayer1Kernel<<<kNRows / 128, 256, 0, stream>>>(points, w1Ptr, b1Ptr, bIdx, bDxy,
                                                      z1, stats);
    ssaLayer2Kernel<<<kNRows / 128, 256, 0, stream>>>(z1, w2Ptr, b2Ptr, g1Ptr, e1Ptr,
                                                      stats, z2, stats + 128);
    ssaLayer3Kernel<<<kNRows / 128, 256, 0, stream>>>(z2, w3Ptr, b3Ptr, g2Ptr, e2Ptr,
                                                      stats + 128, pMax, stats + 256);
    ssaFinalKernel<<<kNB * kC3 * kNS / 256, 256, 0, stream>>>(pMax, stats + 256, stats + 384,
                                                              g3Ptr, e3Ptr,
                                                              outF + kNB * kNS * 3);
}